// Round 11
// baseline (272.868 us; speedup 1.0000x reference)
//
#include <hip/hip_runtime.h>
#include <cstdint>

#define N 8192
#define NT 128     // 64-col chunks per row (N/64)
#define NROUNDS 6  // k_round launches (correctness-independent; k_fix exact)
typedef unsigned long long u64;
typedef unsigned int u32;

__device__ inline u64 readlane64(u64 v, int lane) {
  u32 lo = (u32)__builtin_amdgcn_readlane((int)(u32)v, lane);
  u32 hi = (u32)__builtin_amdgcn_readlane((int)(u32)(v >> 32), lane);
  return ((u64)hi << 32) | lo;
}

// ---------------------------------------------------------------------------
// K1: rank-by-count, FUSED init (replaces k_init+k_rank). Keys are a pure
// function of (score,i) -> recomputed per tile, no keys array, no atomics:
// 32 blocks each scan all 8 chunks and plain-store rank. Also zero-inits
// cnt/prob/y2f (per-element) and D/S (block 0).
// ---------------------------------------------------------------------------
__global__ __launch_bounds__(256) void k_rankz(const float* __restrict__ scores,
                                               int* __restrict__ rank,
                                               int* __restrict__ cnt,
                                               float* __restrict__ prob,
                                               u64* __restrict__ y2f,
                                               u64* __restrict__ D,
                                               u64* __restrict__ S) {
  __shared__ u64 tile[1024];
  int e = blockIdx.x * 256 + threadIdx.x;
  u64 ke = ((u64)__float_as_uint(scores[e]) << 32) | (u32)(0xFFFFFFFFu - (u32)e);
  int c = 0;
  for (int j0 = 0; j0 < N; j0 += 1024) {
    __syncthreads();
    for (int t = threadIdx.x; t < 1024; t += 256) {
      int j = j0 + t;
      tile[t] = ((u64)__float_as_uint(scores[j]) << 32) | (u32)(0xFFFFFFFFu - (u32)j);
    }
    __syncthreads();
#pragma unroll 8
    for (int k = 0; k < 1024; ++k) c += (tile[k] > ke) ? 1 : 0;
  }
  rank[e] = c;                       // stable descending rank
  cnt[e] = 0; prob[e] = 0.0f; y2f[e] = 0ull;
  if (blockIdx.x == 0) {
    if (threadIdx.x < NT) D[threadIdx.x] = 0ull;
    else S[threadIdx.x - NT] = 0ull;
  }
}

// ---------------------------------------------------------------------------
// K2: scatter into sorted SoA (clipped coords, score, area)
// ---------------------------------------------------------------------------
__global__ __launch_bounds__(256) void k_scatter(const float* __restrict__ boxes,
                                                 const float* __restrict__ scores,
                                                 const int* __restrict__ rank,
                                                 float* __restrict__ bx1s, float* __restrict__ by1s,
                                                 float* __restrict__ bx2s, float* __restrict__ by2s,
                                                 float* __restrict__ ss, float* __restrict__ areas) {
#pragma clang fp contract(off)
  int i = blockIdx.x * 256 + threadIdx.x;
  if (i >= N) return;
  int r = rank[i];
  float x1 = fminf(fmaxf(boxes[i * 4 + 0], 0.0f), 1920.0f);
  float y1 = fminf(fmaxf(boxes[i * 4 + 1], 0.0f), 1080.0f);
  float x2 = fminf(fmaxf(boxes[i * 4 + 2], 0.0f), 1920.0f);
  float y2 = fminf(fmaxf(boxes[i * 4 + 3], 0.0f), 1080.0f);
  bx1s[r] = x1; by1s[r] = y1; bx2s[r] = x2; by2s[r] = y2;
  ss[r] = scores[i];
  areas[r] = (x2 - x1 + 1.0f) * (y2 - y1 + 1.0f);
}

// ---------------------------------------------------------------------------
// K3: adjacency, SYMMETRIC lower-triangle, 4 tiles per 256-thread block.
// Band trick (R8, verified absmax 0.0): iou>0.5 <=> 2*inter>uni whenever
// |2*inter-uni| > 1e-6*uni; only in-band lanes take the exact IEEE divide.
// fp contract OFF; matrix float-exact symmetric; ballot transpose mirrors.
// ---------------------------------------------------------------------------
__global__ __launch_bounds__(256) void k_adj(const float* __restrict__ bx1s, const float* __restrict__ by1s,
                                             const float* __restrict__ bx2s, const float* __restrict__ by2s,
                                             const float* __restrict__ areas,
                                             u64* __restrict__ mtile,
                                             u64* __restrict__ mrow) {
#pragma clang fp contract(off)
  __shared__ float jx1[4][64], jy1[4][64], jx2[4][64], jy2[4][64], ja[4][64];
  int w = threadIdx.x >> 6, l = threadIdx.x & 63;
  int p = blockIdx.x * 4 + w;
  int gy = (int)((sqrtf(8.0f * (float)p + 1.0f) - 1.0f) * 0.5f);
  while ((gy + 1) * (gy + 2) / 2 <= p) ++gy;
  while (gy * (gy + 1) / 2 > p) --gy;
  int gx = p - gy * (gy + 1) / 2;

  int j = gx * 64 + l;
  jx1[w][l] = bx1s[j]; jy1[w][l] = by1s[j]; jx2[w][l] = bx2s[j]; jy2[w][l] = by2s[j]; ja[w][l] = areas[j];
  __syncthreads();
  int i = gy * 64 + l;
  float x1 = bx1s[i], y1 = by1s[i], x2 = bx2s[i], y2 = by2s[i], ai = areas[i];
  u64 bits = 0;
#pragma unroll 4
  for (int jj = 0; jj < 64; ++jj) {
    float ix1 = fmaxf(x1, jx1[w][jj]);
    float iy1 = fmaxf(y1, jy1[w][jj]);
    float ix2 = fminf(x2, jx2[w][jj]);
    float iy2 = fminf(y2, jy2[w][jj]);
    float iw = fmaxf(ix2 - ix1 + 1.0f, 0.0f);
    float ih = fmaxf(iy2 - iy1 + 1.0f, 0.0f);
    float inter = iw * ih;
    float uni = (ai + ja[w][jj]) - inter;   // uni > 0 always (areas >= 1)
    float t = inter + inter;                // exact (x2)
    bool gt = t > uni;
    bool amb = fabsf(t - uni) <= 1e-6f * uni;
    if (__ballot(amb) != 0ull) {            // ~never taken
      float iou = inter / uni;              // exact IEEE div, matches numpy
      if (amb) gt = iou > 0.5f;
    }
    bits |= ((u64)gt) << jj;
  }
  mtile[((size_t)gy * NT + gx) * 64 + l] = bits;
  mrow[(size_t)i * NT + gx] = bits;
  if (gx != gy) {
    u64 tb = 0;
#pragma unroll 8
    for (int c = 0; c < 64; ++c) {
      u64 wb = __ballot((bits >> c) & 1ull);
      tb = (l == c) ? wb : tb;
    }
    mtile[((size_t)gx * NT + gy) * 64 + l] = tb;
    mrow[(size_t)(gx * 64 + l) * NT + gy] = tb;
  }
}

// ---------------------------------------------------------------------------
// K4 (x NROUNDS launches): monotone classification round + EXACT in-tile
// resolve. Kernel boundary = free coherent D/S snapshot (R10 lesson: in-kernel
// agent-atomic refresh cost 69us; per-launch plain loads are ~free).
// Rules (sound under staleness): suppressed if some earlier neighbor in D;
// head if ALL earlier neighbors in S. rE tracks EXTERNAL unknown earlier
// neighbors; rE==0 -> prefix classified-and-final for unknown rows -> serial
// diagonal chain resolves the tile EXACTLY. Frontier cascades across
// launches; every published bit is exact, so k_fix stays correct regardless.
// ---------------------------------------------------------------------------
__global__ __launch_bounds__(256) void k_round(const u64* __restrict__ mtile,
                                               u64* __restrict__ D,
                                               u64* __restrict__ S) {
  __shared__ u64 Dl[NT], Sl[NT];
  __shared__ u64 bw[3][4];
  int gy = blockIdx.x;
  int t = threadIdx.x;
  int w = t >> 6, r = t & 63;
  if (t < NT) Dl[t] = D[t];
  else Sl[t - NT] = S[t - NT];
  __syncthreads();
  u64 classified = Dl[gy] | Sl[gy];
  if (classified == ~0ull) return;   // uniform: tile done
  bool unk = !((classified >> r) & 1ull);
  u64 anyD = 0, anyU = 0, anyE = 0;
  if (unk) {
    int k0 = 32 * w, k1 = min(k0 + 32, gy + 1);
    for (int k = k0; k < k1; ++k) {
      u64 m = mtile[((size_t)gy * NT + k) * 64 + r];
      if (k == gy) {
        m &= (1ull << r) - 1ull;       // strictly earlier within own tile
        anyD |= m & Dl[k];
        anyU |= m & ~Sl[k];
      } else {
        anyD |= m & Dl[k];
        anyU |= m & ~Sl[k];
        anyE |= m & ~(Sl[k] | Dl[k]);  // external unknown
      }
    }
  }
  u64 bD = __ballot(anyD != 0ull), bU = __ballot(anyU != 0ull), bE = __ballot(anyE != 0ull);
  if (r == 0) { bw[0][w] = bD; bw[1][w] = bU; bw[2][w] = bE; }
  __syncthreads();
  u64 rD = bw[0][0] | bw[0][1] | bw[0][2] | bw[0][3];
  u64 rU = bw[1][0] | bw[1][1] | bw[1][2] | bw[1][3];
  u64 rE = bw[2][0] | bw[2][1] | bw[2][2] | bw[2][3];
  u64 unkb = ~classified;
  if (rE == 0ull) {
    // exact resolve: every unknown row's earlier prefix is classified-final.
    if (w == 0) {
      u64 dAA = mtile[((size_t)gy * NT + gy) * 64 + r];
      u64 heads = 0, todo = unkb & ~rD;
      while (todo) {
        int i = __builtin_ctzll(todo);
        heads |= 1ull << i;
        todo &= ~readlane64(dAA, i);   // clears i (diag) + in-tile suppressed
      }
      if (r == 0) {
        if (heads) atomicOr(&D[gy], heads);
        u64 ns = unkb & ~heads;
        if (ns) atomicOr(&S[gy], ns);
      }
    }
    return;
  }
  if (t == 0) {
    u64 newS = unkb & rD;
    u64 newD = unkb & ~rD & ~rU;
    if (newS) atomicOr(&S[gy], newS);
    if (newD) atomicOr(&D[gy], newD);
  }
}

// ---------------------------------------------------------------------------
// K5: exact serial cleanup, ONE wave, branchless chain (R9). With the
// resolve cascade, M should be ~0; kept for unconditional correctness.
// ---------------------------------------------------------------------------
__global__ __launch_bounds__(64, 1) void k_fix(const u64* __restrict__ mrow,
                                               u64* __restrict__ D,
                                               const u64* __restrict__ S) {
  __shared__ int ulist[N];
  int l = threadIdx.x;
  u64 D0 = D[2 * l], D1 = D[2 * l + 1];
  u64 S0 = S[2 * l], S1 = S[2 * l + 1];
  u64 u0 = ~(D0 | S0), u1 = ~(D1 | S1);
  int cnt = __popcll(u0) + __popcll(u1);
  int pre = cnt;
  for (int d = 1; d < 64; d <<= 1) {
    int v = __shfl_up(pre, d);
    if (l >= d) pre += v;
  }
  int M = __shfl(pre, 63);
  int off = pre - cnt;
  {
    u64 v = u0; int o = off;
    while (v) { int b = __builtin_ctzll(v); v &= v - 1; ulist[o++] = l * 128 + b; }
    v = u1;
    while (v) { int b = __builtin_ctzll(v); v &= v - 1; ulist[o++] = l * 128 + 64 + b; }
  }
  __syncthreads();
  if (M > 0) {
    ulong2 ring[8];
    int pj[8];
#pragma unroll
    for (int q = 0; q < 8; ++q) {
      int j = ulist[q < M ? q : M - 1];
      pj[q] = j;
      ring[q] = *(const ulong2*)&mrow[(size_t)j * NT + 2 * l];
    }
    for (int m = 0; m < M; ++m) {
      int slot = m & 7;
      int j = pj[slot];
      ulong2 rv = ring[slot];
      int jt = j >> 6;
      u64 bm = (1ull << (j & 63)) - 1ull;
      u64 m0 = (2 * l < jt) ? ~0ull : ((2 * l == jt) ? bm : 0ull);
      u64 m1 = (2 * l + 1 < jt) ? ~0ull : ((2 * l + 1 == jt) ? bm : 0ull);
      bool hit = ((rv.x & D0 & m0) | (rv.y & D1 & m1)) != 0ull;
      bool head = (__ballot(hit) == 0ull);
      u64 bset = 1ull << (j & 63);
      D0 |= (head && (2 * l == jt)) ? bset : 0ull;
      D1 |= (head && (2 * l + 1 == jt)) ? bset : 0ull;
      int nm = m + 8;
      int j2 = ulist[nm < M ? nm : M - 1];
      pj[slot] = j2;
      ring[slot] = *(const ulong2*)&mrow[(size_t)j2 * NT + 2 * l];
    }
  }
  D[2 * l] = D0;
  D[2 * l + 1] = D1;
}

// ---------------------------------------------------------------------------
// K6: parallel cluster assignment + segment atomics. cluster[j] = first head
// adjacent to j (symmetry). Packed y2f = (by2_bits<<32)|~j: one u64 atomicMax
// gives max-by2 with min-j tiebreak == reference's `first` (kills k_first).
// ---------------------------------------------------------------------------
__global__ __launch_bounds__(256) void k_cluster(const u64* __restrict__ mtile,
                                                 const u64* __restrict__ D,
                                                 const float* __restrict__ ss,
                                                 const float* __restrict__ by2s,
                                                 int* __restrict__ cluster,
                                                 int* __restrict__ cnt,
                                                 float* __restrict__ prob,
                                                 u64* __restrict__ y2f) {
  __shared__ u64 hlds[NT];
  __shared__ int red[4][64];
  int gy = blockIdx.x;
  if (threadIdx.x < NT) hlds[threadIdx.x] = D[threadIdx.x];
  __syncthreads();
  int w = threadIdx.x >> 6, r = threadIdx.x & 63;
  int best = 0x7fffffff;
  for (int kk = 0; kk < 32; ++kk) {
    int k = 32 * w + kk;
    u64 v = mtile[((size_t)gy * NT + k) * 64 + r] & hlds[k];
    if (v && best == 0x7fffffff) best = k * 64 + __builtin_ctzll(v);
  }
  red[w][r] = best;
  __syncthreads();
  if (w == 0) {
    int b = min(min(red[0][r], red[1][r]), min(red[2][r], red[3][r]));
    int j = gy * 64 + r;
    cluster[j] = b;
    atomicAdd(&cnt[b], 1);
    atomicAdd(&prob[b], ss[j]);
    u64 key = ((u64)__float_as_uint(by2s[j]) << 32) | (u32)(0xFFFFFFFFu - (u32)j);
    atomicMax(&y2f[b], key);           // by2 > 0 -> bits order == float order
  }
}

// ---------------------------------------------------------------------------
// K7: outputs. out[j][0..4] then keep[j] appended (floats 0/1).
// ---------------------------------------------------------------------------
__global__ __launch_bounds__(256) void k_out(const int* __restrict__ cluster,
                                             const float* __restrict__ bx1s, const float* __restrict__ by1s,
                                             const float* __restrict__ bx2s, const float* __restrict__ by2s,
                                             const int* __restrict__ cnt,
                                             const float* __restrict__ prob,
                                             const u64* __restrict__ y2f,
                                             const int* __restrict__ num_models,
                                             float* __restrict__ out) {
  int j = blockIdx.x * 256 + threadIdx.x;
  if (j >= N) return;
  int c = cluster[j];
  int nm = num_models[0];
  bool valid = (float)cnt[c] >= (float)nm / 3.0f;
  int jf = (int)(0xFFFFFFFFu - (u32)(y2f[c] & 0xFFFFFFFFull));
  bool keep = (jf == j) && valid;
  float o0 = 0.f, o1 = 0.f, o2 = 0.f, o3 = 0.f, o4 = 0.f;
  if (keep) {
    o0 = bx1s[j]; o1 = by1s[j]; o2 = bx2s[j]; o3 = by2s[j];
    o4 = prob[c] / (float)nm;
  }
  out[j * 5 + 0] = o0;
  out[j * 5 + 1] = o1;
  out[j * 5 + 2] = o2;
  out[j * 5 + 3] = o3;
  out[j * 5 + 4] = o4;
  out[N * 5 + j] = keep ? 1.0f : 0.0f;
}

// ---------------------------------------------------------------------------
extern "C" void kernel_launch(void* const* d_in, const int* in_sizes, int n_in,
                              void* d_out, int out_size, void* d_ws, size_t ws_size,
                              hipStream_t stream) {
  const float* boxes = (const float*)d_in[0];
  const float* scores = (const float*)d_in[1];
  const int* num_models = (const int*)d_in[2];
  float* out = (float*)d_out;

  char* p = (char*)d_ws;
  auto take = [&](size_t bytes) {
    char* r = p;
    p += (bytes + 255) & ~(size_t)255;
    return r;
  };
  int* rank   = (int*)take((size_t)N * 4);
  float* bx1s = (float*)take((size_t)N * 4);
  float* by1s = (float*)take((size_t)N * 4);
  float* bx2s = (float*)take((size_t)N * 4);
  float* by2s = (float*)take((size_t)N * 4);
  float* ss   = (float*)take((size_t)N * 4);
  float* areas= (float*)take((size_t)N * 4);
  int* cluster= (int*)take((size_t)N * 4);
  int* cnt    = (int*)take((size_t)N * 4);
  float* prob = (float*)take((size_t)N * 4);
  u64* y2f    = (u64*)take((size_t)N * 8);            // packed (by2,~j)
  u64* D      = (u64*)take((size_t)NT * 8);           // head bitmap
  u64* S      = (u64*)take((size_t)NT * 8);           // suppressed bitmap
  u64* mtile  = (u64*)take((size_t)NT * NT * 64 * 8); // 8 MiB tiled adjacency
  u64* mrow   = (u64*)take((size_t)N * NT * 8);       // 8 MiB row-major adjacency

  k_rankz<<<N / 256, 256, 0, stream>>>(scores, rank, cnt, prob, y2f, D, S);
  k_scatter<<<N / 256, 256, 0, stream>>>(boxes, scores, rank, bx1s, by1s, bx2s, by2s, ss, areas);
  k_adj<<<NT * (NT + 1) / 2 / 4, 256, 0, stream>>>(bx1s, by1s, bx2s, by2s, areas, mtile, mrow);
  for (int r = 0; r < NROUNDS; ++r)
    k_round<<<NT, 256, 0, stream>>>(mtile, D, S);
  k_fix<<<1, 64, 0, stream>>>(mrow, D, S);
  k_cluster<<<N / 64, 256, 0, stream>>>(mtile, D, ss, by2s, cluster, cnt, prob, y2f);
  k_out<<<N / 256, 256, 0, stream>>>(cluster, bx1s, by1s, bx2s, by2s, cnt, prob, y2f, num_models, out);
}

// Round 12
// 177.688 us; speedup vs baseline: 1.5357x; 1.5357x over previous
//
#include <hip/hip_runtime.h>
#include <cstdint>

#define N 8192
#define NT 128     // 64-col chunks per row (N/64)
#define NROUNDS 6  // k_round launches (correctness-independent; k_fix exact)
typedef unsigned long long u64;
typedef unsigned int u32;

__device__ inline u64 readlane64(u64 v, int lane) {
  u32 lo = (u32)__builtin_amdgcn_readlane((int)(u32)v, lane);
  u32 hi = (u32)__builtin_amdgcn_readlane((int)(u32)(v >> 32), lane);
  return ((u64)hi << 32) | lo;
}

// ---------------------------------------------------------------------------
// K1: rank + scatter + init, 256 blocks (R11 lesson: k_rankz at 32 blocks ran
// 12% of the machine -> 119us; same work at 256 blocks + full-thread stages).
// Block b owns elements [32b, 32b+32). Thread (s=t>>5, e=t&31) counts keys
// greater than element e's key within sub-slice s of each staged 1KB chunk.
// Keys recomputed from scores (pure function; no keys array, no atomics).
// After LDS reduce, threads t<32 scatter their element into the sorted SoA
// (kills k_scatter) and zero-init per-element aux; block 0 zeroes D/S.
// ---------------------------------------------------------------------------
__global__ __launch_bounds__(256) void k_rank0(const float* __restrict__ scores,
                                               const float* __restrict__ boxes,
                                               float* __restrict__ bx1s, float* __restrict__ by1s,
                                               float* __restrict__ bx2s, float* __restrict__ by2s,
                                               float* __restrict__ ss, float* __restrict__ areas,
                                               int* __restrict__ cnt,
                                               float* __restrict__ prob,
                                               u64* __restrict__ y2f,
                                               u64* __restrict__ D,
                                               u64* __restrict__ S) {
#pragma clang fp contract(off)
  __shared__ u64 tile[1024];
  __shared__ int red[8][32];
  int t = threadIdx.x;
  int s = t >> 5, ei = t & 31;
  int e = blockIdx.x * 32 + ei;
  u64 ke = ((u64)__float_as_uint(scores[e]) << 32) | (u32)(0xFFFFFFFFu - (u32)e);
  int c = 0;
  for (int j0 = 0; j0 < N; j0 += 1024) {
    __syncthreads();
    for (int q = t; q < 1024; q += 256) {
      int j = j0 + q;
      tile[q] = ((u64)__float_as_uint(scores[j]) << 32) | (u32)(0xFFFFFFFFu - (u32)j);
    }
    __syncthreads();
    int k0 = s * 128;
#pragma unroll 8
    for (int k = 0; k < 128; ++k) c += (tile[k0 + k] > ke) ? 1 : 0;
  }
  red[s][ei] = c;
  __syncthreads();
  if (t < 32) {
    int r = 0;
#pragma unroll
    for (int q = 0; q < 8; ++q) r += red[q][t];
    int i = blockIdx.x * 32 + t;
    float x1 = fminf(fmaxf(boxes[i * 4 + 0], 0.0f), 1920.0f);
    float y1 = fminf(fmaxf(boxes[i * 4 + 1], 0.0f), 1080.0f);
    float x2 = fminf(fmaxf(boxes[i * 4 + 2], 0.0f), 1920.0f);
    float y2 = fminf(fmaxf(boxes[i * 4 + 3], 0.0f), 1080.0f);
    bx1s[r] = x1; by1s[r] = y1; bx2s[r] = x2; by2s[r] = y2;
    ss[r] = scores[i];
    areas[r] = (x2 - x1 + 1.0f) * (y2 - y1 + 1.0f);
    cnt[i] = 0; prob[i] = 0.0f; y2f[i] = 0ull;
  }
  if (blockIdx.x == 0) {
    if (t < NT) D[t] = 0ull;
    else if (t < 2 * NT) S[t - NT] = 0ull;
  }
}

// ---------------------------------------------------------------------------
// K2: adjacency, SYMMETRIC lower-triangle, 4 tiles per 256-thread block.
// Band trick (R8, verified absmax 0.0): iou>0.5 <=> 2*inter>uni whenever
// |2*inter-uni| > 1e-6*uni; only in-band lanes take the exact IEEE divide.
// fp contract OFF; matrix float-exact symmetric; ballot transpose mirrors.
// mrow dropped (R12): k_fix reads mtile directly; halves adjacency writes.
// ---------------------------------------------------------------------------
__global__ __launch_bounds__(256) void k_adj(const float* __restrict__ bx1s, const float* __restrict__ by1s,
                                             const float* __restrict__ bx2s, const float* __restrict__ by2s,
                                             const float* __restrict__ areas,
                                             u64* __restrict__ mtile) {
#pragma clang fp contract(off)
  __shared__ float jx1[4][64], jy1[4][64], jx2[4][64], jy2[4][64], ja[4][64];
  int w = threadIdx.x >> 6, l = threadIdx.x & 63;
  int p = blockIdx.x * 4 + w;
  int gy = (int)((sqrtf(8.0f * (float)p + 1.0f) - 1.0f) * 0.5f);
  while ((gy + 1) * (gy + 2) / 2 <= p) ++gy;
  while (gy * (gy + 1) / 2 > p) --gy;
  int gx = p - gy * (gy + 1) / 2;

  int j = gx * 64 + l;
  jx1[w][l] = bx1s[j]; jy1[w][l] = by1s[j]; jx2[w][l] = bx2s[j]; jy2[w][l] = by2s[j]; ja[w][l] = areas[j];
  __syncthreads();
  int i = gy * 64 + l;
  float x1 = bx1s[i], y1 = by1s[i], x2 = bx2s[i], y2 = by2s[i], ai = areas[i];
  u64 bits = 0;
#pragma unroll 4
  for (int jj = 0; jj < 64; ++jj) {
    float ix1 = fmaxf(x1, jx1[w][jj]);
    float iy1 = fmaxf(y1, jy1[w][jj]);
    float ix2 = fminf(x2, jx2[w][jj]);
    float iy2 = fminf(y2, jy2[w][jj]);
    float iw = fmaxf(ix2 - ix1 + 1.0f, 0.0f);
    float ih = fmaxf(iy2 - iy1 + 1.0f, 0.0f);
    float inter = iw * ih;
    float uni = (ai + ja[w][jj]) - inter;   // uni > 0 always (areas >= 1)
    float t = inter + inter;                // exact (x2)
    bool gt = t > uni;
    bool amb = fabsf(t - uni) <= 1e-6f * uni;
    if (__ballot(amb) != 0ull) {            // ~never taken
      float iou = inter / uni;              // exact IEEE div, matches numpy
      if (amb) gt = iou > 0.5f;
    }
    bits |= ((u64)gt) << jj;
  }
  mtile[((size_t)gy * NT + gx) * 64 + l] = bits;
  if (gx != gy) {
    u64 tb = 0;
#pragma unroll 8
    for (int c = 0; c < 64; ++c) {
      u64 wb = __ballot((bits >> c) & 1ull);
      tb = (l == c) ? wb : tb;
    }
    mtile[((size_t)gx * NT + gy) * 64 + l] = tb;
  }
}

// ---------------------------------------------------------------------------
// K3 (x NROUNDS launches): monotone classification round + EXACT in-tile
// resolve (R11, validated). Kernel boundary = free coherent D/S snapshot.
// Rules (sound under staleness): suppressed if some earlier neighbor in D;
// head if ALL earlier neighbors in S. rE==0 -> prefix final -> serial
// diagonal chain resolves the tile EXACTLY; frontier cascades across
// launches. Every published bit is exact; k_fix stays correct regardless.
// ---------------------------------------------------------------------------
__global__ __launch_bounds__(256) void k_round(const u64* __restrict__ mtile,
                                               u64* __restrict__ D,
                                               u64* __restrict__ S) {
  __shared__ u64 Dl[NT], Sl[NT];
  __shared__ u64 bw[3][4];
  int gy = blockIdx.x;
  int t = threadIdx.x;
  int w = t >> 6, r = t & 63;
  if (t < NT) Dl[t] = D[t];
  else Sl[t - NT] = S[t - NT];
  __syncthreads();
  u64 classified = Dl[gy] | Sl[gy];
  if (classified == ~0ull) return;   // uniform: tile done
  bool unk = !((classified >> r) & 1ull);
  u64 anyD = 0, anyU = 0, anyE = 0;
  if (unk) {
    int k0 = 32 * w, k1 = min(k0 + 32, gy + 1);
    for (int k = k0; k < k1; ++k) {
      u64 m = mtile[((size_t)gy * NT + k) * 64 + r];
      if (k == gy) {
        m &= (1ull << r) - 1ull;       // strictly earlier within own tile
        anyD |= m & Dl[k];
        anyU |= m & ~Sl[k];
      } else {
        anyD |= m & Dl[k];
        anyU |= m & ~Sl[k];
        anyE |= m & ~(Sl[k] | Dl[k]);  // external unknown
      }
    }
  }
  u64 bD = __ballot(anyD != 0ull), bU = __ballot(anyU != 0ull), bE = __ballot(anyE != 0ull);
  if (r == 0) { bw[0][w] = bD; bw[1][w] = bU; bw[2][w] = bE; }
  __syncthreads();
  u64 rD = bw[0][0] | bw[0][1] | bw[0][2] | bw[0][3];
  u64 rU = bw[1][0] | bw[1][1] | bw[1][2] | bw[1][3];
  u64 rE = bw[2][0] | bw[2][1] | bw[2][2] | bw[2][3];
  u64 unkb = ~classified;
  if (rE == 0ull) {
    if (w == 0) {
      u64 dAA = mtile[((size_t)gy * NT + gy) * 64 + r];
      u64 heads = 0, todo = unkb & ~rD;
      while (todo) {
        int i = __builtin_ctzll(todo);
        heads |= 1ull << i;
        todo &= ~readlane64(dAA, i);   // clears i (diag) + in-tile suppressed
      }
      if (r == 0) {
        if (heads) atomicOr(&D[gy], heads);
        u64 ns = unkb & ~heads;
        if (ns) atomicOr(&S[gy], ns);
      }
    }
    return;
  }
  if (t == 0) {
    u64 newS = unkb & rD;
    u64 newD = unkb & ~rD & ~rU;
    if (newS) atomicOr(&S[gy], newS);
    if (newD) atomicOr(&D[gy], newD);
  }
}

// ---------------------------------------------------------------------------
// K4: exact serial cleanup, ONE wave, branchless chain. Lane l owns D/S
// words l and 64+l (matches mtile lane-per-chunk row fetch: lane l loads
// row j's chunk-l and chunk-(64+l) words, 2 strided 8B loads, 8-deep ring).
// ulist built in ascending global order via two-phase prefix scan.
// Invariant: when row j is tested, D contains ALL true heads < j ->
// (row_j & D & below)==0 <=> head. Exact for ANY round state; M~0 expected.
// ---------------------------------------------------------------------------
__global__ __launch_bounds__(64, 1) void k_fix(const u64* __restrict__ mtile,
                                               u64* __restrict__ D,
                                               const u64* __restrict__ S) {
  __shared__ int ulist[N];
  int l = threadIdx.x;
  u64 D0 = D[l], D1 = D[64 + l];
  u64 S0 = S[l], S1 = S[64 + l];
  u64 u0 = ~(D0 | S0), u1 = ~(D1 | S1);
  int c0 = __popcll(u0), c1 = __popcll(u1);
  int p0 = c0, p1 = c1;
  for (int d = 1; d < 64; d <<= 1) {
    int v0 = __shfl_up(p0, d), v1 = __shfl_up(p1, d);
    if (l >= d) { p0 += v0; p1 += v1; }
  }
  int t0 = __shfl(p0, 63);
  int M = t0 + __shfl(p1, 63);
  {
    int o = p0 - c0;
    u64 v = u0;
    while (v) { int b = __builtin_ctzll(v); v &= v - 1; ulist[o++] = l * 64 + b; }
    o = t0 + p1 - c1;
    v = u1;
    while (v) { int b = __builtin_ctzll(v); v &= v - 1; ulist[o++] = (64 + l) * 64 + b; }
  }
  __syncthreads();
  if (M > 0) {
    u64 rx[8], ry[8];
    int pj[8];
    auto fetch = [&](int q, int j) {
      pj[q] = j;
      int jt = j >> 6, jl = j & 63;
      rx[q] = mtile[((size_t)jt * NT + l) * 64 + jl];
      ry[q] = mtile[((size_t)jt * NT + 64 + l) * 64 + jl];
    };
#pragma unroll
    for (int q = 0; q < 8; ++q) fetch(q, ulist[q < M ? q : M - 1]);
    for (int m = 0; m < M; ++m) {
      int slot = m & 7;
      int j = pj[slot];
      u64 vx = rx[slot], vy = ry[slot];
      int jt = j >> 6;                       // uniform
      u64 bm = (1ull << (j & 63)) - 1ull;
      u64 m0 = (l < jt) ? ~0ull : ((l == jt) ? bm : 0ull);
      u64 m1 = (64 + l < jt) ? ~0ull : ((64 + l == jt) ? bm : 0ull);
      bool hit = ((vx & D0 & m0) | (vy & D1 & m1)) != 0ull;
      bool head = (__ballot(hit) == 0ull);   // uniform
      u64 bset = 1ull << (j & 63);
      D0 |= (head && (l == jt)) ? bset : 0ull;
      D1 |= (head && (64 + l == jt)) ? bset : 0ull;
      int nm = m + 8;
      fetch(slot, ulist[nm < M ? nm : M - 1]);
    }
  }
  D[l] = D0;
  D[64 + l] = D1;
}

// ---------------------------------------------------------------------------
// K5: parallel cluster assignment + segment atomics. cluster[j] = first head
// adjacent to j (symmetry). Packed y2f = (by2_bits<<32)|~j: one u64 atomicMax
// gives max-by2 with min-j tiebreak == reference's `first` (R11, validated).
// ---------------------------------------------------------------------------
__global__ __launch_bounds__(256) void k_cluster(const u64* __restrict__ mtile,
                                                 const u64* __restrict__ D,
                                                 const float* __restrict__ ss,
                                                 const float* __restrict__ by2s,
                                                 int* __restrict__ cluster,
                                                 int* __restrict__ cnt,
                                                 float* __restrict__ prob,
                                                 u64* __restrict__ y2f) {
  __shared__ u64 hlds[NT];
  __shared__ int red[4][64];
  int gy = blockIdx.x;
  if (threadIdx.x < NT) hlds[threadIdx.x] = D[threadIdx.x];
  __syncthreads();
  int w = threadIdx.x >> 6, r = threadIdx.x & 63;
  int best = 0x7fffffff;
  for (int kk = 0; kk < 32; ++kk) {
    int k = 32 * w + kk;
    u64 v = mtile[((size_t)gy * NT + k) * 64 + r] & hlds[k];
    if (v && best == 0x7fffffff) best = k * 64 + __builtin_ctzll(v);
  }
  red[w][r] = best;
  __syncthreads();
  if (w == 0) {
    int b = min(min(red[0][r], red[1][r]), min(red[2][r], red[3][r]));
    int j = gy * 64 + r;
    cluster[j] = b;
    atomicAdd(&cnt[b], 1);
    atomicAdd(&prob[b], ss[j]);
    u64 key = ((u64)__float_as_uint(by2s[j]) << 32) | (u32)(0xFFFFFFFFu - (u32)j);
    atomicMax(&y2f[b], key);           // by2 > 0 -> bits order == float order
  }
}

// ---------------------------------------------------------------------------
// K6: outputs. out[j][0..4] then keep[j] appended (floats 0/1).
// ---------------------------------------------------------------------------
__global__ __launch_bounds__(256) void k_out(const int* __restrict__ cluster,
                                             const float* __restrict__ bx1s, const float* __restrict__ by1s,
                                             const float* __restrict__ bx2s, const float* __restrict__ by2s,
                                             const int* __restrict__ cnt,
                                             const float* __restrict__ prob,
                                             const u64* __restrict__ y2f,
                                             const int* __restrict__ num_models,
                                             float* __restrict__ out) {
  int j = blockIdx.x * 256 + threadIdx.x;
  if (j >= N) return;
  int c = cluster[j];
  int nm = num_models[0];
  bool valid = (float)cnt[c] >= (float)nm / 3.0f;
  int jf = (int)(0xFFFFFFFFu - (u32)(y2f[c] & 0xFFFFFFFFull));
  bool keep = (jf == j) && valid;
  float o0 = 0.f, o1 = 0.f, o2 = 0.f, o3 = 0.f, o4 = 0.f;
  if (keep) {
    o0 = bx1s[j]; o1 = by1s[j]; o2 = bx2s[j]; o3 = by2s[j];
    o4 = prob[c] / (float)nm;
  }
  out[j * 5 + 0] = o0;
  out[j * 5 + 1] = o1;
  out[j * 5 + 2] = o2;
  out[j * 5 + 3] = o3;
  out[j * 5 + 4] = o4;
  out[N * 5 + j] = keep ? 1.0f : 0.0f;
}

// ---------------------------------------------------------------------------
extern "C" void kernel_launch(void* const* d_in, const int* in_sizes, int n_in,
                              void* d_out, int out_size, void* d_ws, size_t ws_size,
                              hipStream_t stream) {
  const float* boxes = (const float*)d_in[0];
  const float* scores = (const float*)d_in[1];
  const int* num_models = (const int*)d_in[2];
  float* out = (float*)d_out;

  char* p = (char*)d_ws;
  auto take = [&](size_t bytes) {
    char* r = p;
    p += (bytes + 255) & ~(size_t)255;
    return r;
  };
  float* bx1s = (float*)take((size_t)N * 4);
  float* by1s = (float*)take((size_t)N * 4);
  float* bx2s = (float*)take((size_t)N * 4);
  float* by2s = (float*)take((size_t)N * 4);
  float* ss   = (float*)take((size_t)N * 4);
  float* areas= (float*)take((size_t)N * 4);
  int* cluster= (int*)take((size_t)N * 4);
  int* cnt    = (int*)take((size_t)N * 4);
  float* prob = (float*)take((size_t)N * 4);
  u64* y2f    = (u64*)take((size_t)N * 8);            // packed (by2,~j)
  u64* D      = (u64*)take((size_t)NT * 8);           // head bitmap
  u64* S      = (u64*)take((size_t)NT * 8);           // suppressed bitmap
  u64* mtile  = (u64*)take((size_t)NT * NT * 64 * 8); // 8 MiB tiled adjacency

  k_rank0<<<N / 32, 256, 0, stream>>>(scores, boxes, bx1s, by1s, bx2s, by2s, ss, areas,
                                      cnt, prob, y2f, D, S);
  k_adj<<<NT * (NT + 1) / 2 / 4, 256, 0, stream>>>(bx1s, by1s, bx2s, by2s, areas, mtile);
  for (int r = 0; r < NROUNDS; ++r)
    k_round<<<NT, 256, 0, stream>>>(mtile, D, S);
  k_fix<<<1, 64, 0, stream>>>(mtile, D, S);
  k_cluster<<<N / 64, 256, 0, stream>>>(mtile, D, ss, by2s, cluster, cnt, prob, y2f);
  k_out<<<N / 256, 256, 0, stream>>>(cluster, bx1s, by1s, bx2s, by2s, cnt, prob, y2f, num_models, out);
}